// Round 4
// baseline (631.089 us; speedup 1.0000x reference)
//
#include <hip/hip_runtime.h>

typedef __bf16 bf16;
typedef __bf16 bf16x8 __attribute__((ext_vector_type(8)));
typedef __bf16 bf16x4 __attribute__((ext_vector_type(4)));
typedef float  f32x4  __attribute__((ext_vector_type(4)));

// ---------------------------------------------------------------------------
// f32 -> bf16 convert, 4-wide
// ---------------------------------------------------------------------------
__global__ void f2b_kernel(const float* __restrict__ src, bf16* __restrict__ dst, int n4) {
    int i = blockIdx.x * 256 + threadIdx.x;
    if (i >= n4) return;
    float4 v = ((const float4*)src)[i];
    bf16x4 o = { (bf16)v.x, (bf16)v.y, (bf16)v.z, (bf16)v.w };
    ((bf16x4*)dst)[i] = o;
}

// ---------------------------------------------------------------------------
// Swizzle fp32 W (taps, cin, cout) into bf16 MFMA-B-fragment order:
//   Wf[tap][s][nt][lane][j] = W[tap][s*32 + (lane>>4)*8 + j][nt*16 + (lane&15)]
// ---------------------------------------------------------------------------
__global__ void swz_kernel(const float* __restrict__ W, bf16* __restrict__ Wf,
                           int cin, int cout, int total) {
    int e = blockIdx.x * 256 + threadIdx.x;
    if (e >= total) return;
    int per_tap = cin * cout;
    int tap = e / per_tap;
    int t2  = e - tap * per_tap;
    int ntc = cout >> 4;               // number of 16-col tiles
    int s   = t2 / (ntc * 512);        // K-step of 32
    int r3  = t2 - s * (ntc * 512);
    int nt  = r3 >> 9;
    int L   = (r3 & 511) >> 3;
    int j   = r3 & 7;
    int k   = s * 32 + (L >> 4) * 8 + j;
    int col = nt * 16 + (L & 15);
    Wf[e] = (bf16)W[((size_t)tap * cin + k) * cout + col];
}

// ---------------------------------------------------------------------------
// ROUND-4 STRUCTURE: one wave per block, ZERO barriers.
// R1-R3 post-mortem: every pipelining variant of the 4-wave barrier design
// landed at ~130-145us for b1 (MfmaUtil 20-22, VALUBusy 23-25, nothing
// saturated) -> the gang-stall topology itself was the bottleneck, not
// prefetch depth. Here each 64-thread block is ONE independent wave owning
// RW rows. The MFMA A-fragment (lane l: row l&15, 16B at k-ofs quad*8) is
// gathered DIRECTLY global->VGPR per lane -- no LDS staging tile, no
// ds_write/ds_read for A, no s_barrier anywhere. 1-step register prefetch
// (flat tap*KS step loop) keeps gathers+weights in flight under the MFMAs;
// waves self-schedule, never gang-stall. Dense stages round-trip a PRIVATE
// per-wave LDS tile (within-wave lgkmcnt ordering only).
// ---------------------------------------------------------------------------
template<int CIN, int C1, int TAPS, int C2, int C3>
__global__ __launch_bounds__(64, 2) void layer_kernel(
    const bf16* __restrict__ X,
    const bf16* __restrict__ W1,     // swizzled (TAPS, CIN/32, C1/16, 512)
    const bf16* __restrict__ W2,     // swizzled (C1/32, C2/16, 512)
    const bf16* __restrict__ W3,     // swizzled (C2/32, C3/16, 512) or null
    const int*  __restrict__ nbr,    // (TAPS, n)
    const float* __restrict__ sc1, const float* __restrict__ sh1,
    const float* __restrict__ sc2, const float* __restrict__ sh2,
    const float* __restrict__ sc3, const float* __restrict__ sh3,
    bf16* __restrict__ Y, float* __restrict__ Yf,
    int ystride, int yoff, int n, int nblocks)
{
    constexpr int NT1 = C1 / 16;
    constexpr int WC1 = NT1;                 // wave covers full output width
    constexpr int WR1 = (C1 >= 128) ? 2 : 4; // row-tiles per wave (VGPR budget)
    constexpr int RW  = WR1 * 16;            // rows per wave
    constexpr int KS  = CIN / 32;            // K-slices per tap
    constexpr int TOT = TAPS * KS;           // flat step count
    constexpr int LS1 = C1 + 8;
    constexpr int LS2 = C2 + 8;
    constexpr int LSM = (LS1 > LS2) ? LS1 : LS2;

    __shared__ __align__(16) bf16 Lt[RW * LSM];   // private: one wave per block

    const int lane = threadIdx.x;            // 0..63
    const int m16  = lane & 15;
    const int quad = lane >> 4;

    // XCD-contiguous block swizzle (bijection, m204 form)
    const int bq = nblocks >> 3, br = nblocks & 7;
    const int bx = blockIdx.x & 7, bs = blockIdx.x >> 3;
    const int sb = bx * bq + (bx < br ? bx : br) + bs;
    const int base = sb * RW;

    const bf16x8 ZB = __builtin_bit_cast(bf16x8, (float4){0.f, 0.f, 0.f, 0.f});

    int idxc[WR1], idxn[WR1];
    auto load_idx = [&](int t, int (&id)[WR1]) {
#pragma unroll
        for (int r = 0; r < WR1; ++r)
            id[r] = nbr[(size_t)t * n + base + r * 16 + m16];
    };
    auto load_b = [&](int step, bf16x8 (&b)[WC1]) {
        const bf16* wt = W1 + (size_t)step * (NT1 * 512) + lane * 8;
#pragma unroll
        for (int c = 0; c < WC1; ++c)
            b[c] = *(const bf16x8*)(wt + c * 512);
    };

    f32x4 acc1[WR1][WC1];
#pragma unroll
    for (int r = 0; r < WR1; ++r)
#pragma unroll
        for (int c = 0; c < WC1; ++c) acc1[r][c] = (f32x4){0.f, 0.f, 0.f, 0.f};

    bf16x8 aA[WR1], aB[WR1], bA[WC1], bB[WC1];

    // prologue: step (0,0) into A-buffers; indices for taps 0 and 1
    load_idx(0, idxc);
    load_idx(1, idxn);
    load_b(0, bA);
#pragma unroll
    for (int r = 0; r < WR1; ++r) {
        bf16x8 v = ZB;
        int id_ = idxc[r];
        if (id_ >= 0) v = *(const bf16x8*)(X + (unsigned)id_ * CIN + quad * 8);
        aA[r] = v;
    }

    int t = 0, s = 0;
    auto step = [&](int it, bf16x8 (&aC)[WR1], bf16x8 (&bC)[WC1],
                    bf16x8 (&aN)[WR1], bf16x8 (&bN)[WC1]) {
        int s1 = s + 1, t1 = t;
        bool wrap = (s1 == KS);
        if (wrap) { s1 = 0; ++t1; }
        if (it + 1 < TOT) {
            load_b(t1 * KS + s1, bN);                // next-step weights
#pragma unroll
            for (int r = 0; r < WR1; ++r) {          // next-step gather
                int id_ = wrap ? idxn[r] : idxc[r];
                bf16x8 v = ZB;
                if (id_ >= 0) v = *(const bf16x8*)(X + (unsigned)id_ * CIN + s1 * 32 + quad * 8);
                aN[r] = v;
            }
        }
#pragma unroll
        for (int r = 0; r < WR1; ++r)
#pragma unroll
            for (int c = 0; c < WC1; ++c)
                acc1[r][c] = __builtin_amdgcn_mfma_f32_16x16x32_bf16(aC[r], bC[c], acc1[r][c], 0, 0, 0);
        if (wrap) {
#pragma unroll
            for (int r = 0; r < WR1; ++r) idxc[r] = idxn[r];
            if (t + 2 < TAPS) load_idx(t + 2, idxn); // indices two taps ahead
        }
        t = t1; s = s1;
    };

    for (int it = 0; it < TOT; it += 2) {
        step(it, aA, bA, aB, bB);
        if (it + 1 < TOT) step(it + 1, aB, bB, aA, bA);
    }

    // ---- stage-1 epilogue -> private LDS tile (bf16); no barrier needed ----
#pragma unroll
    for (int c = 0; c < WC1; ++c) {
        int col = c * 16 + m16;
        float sc = sc1[col], sh = sh1[col];
#pragma unroll
        for (int r = 0; r < WR1; ++r) {
            int row0 = r * 16 + quad * 4;
#pragma unroll
            for (int i = 0; i < 4; ++i) {
                float v = acc1[r][c][i] * sc + sh;
                v = v > 0.f ? v : 0.f;
                Lt[(row0 + i) * LS1 + col] = (bf16)v;
            }
        }
    }

    // ---- stage 2: dense GEMM K=C1 (within-wave; lgkmcnt orders Lt) ----
    constexpr int NT2 = C2 / 16;
    constexpr int WC2 = NT2;
    constexpr int KS2 = C1 / 32;

    f32x4 acc2[WR1][WC2];
#pragma unroll
    for (int r = 0; r < WR1; ++r)
#pragma unroll
        for (int c = 0; c < WC2; ++c) acc2[r][c] = (f32x4){0.f, 0.f, 0.f, 0.f};

#pragma unroll
    for (int s2 = 0; s2 < KS2; ++s2) {
        bf16x8 a[WR1], bw[WC2];
#pragma unroll
        for (int r = 0; r < WR1; ++r)
            a[r] = *(const bf16x8*)(&Lt[(r * 16 + m16) * LS1 + s2 * 32 + quad * 8]);
#pragma unroll
        for (int c = 0; c < WC2; ++c)
            bw[c] = *(const bf16x8*)(W2 + ((s2 * NT2 + c) * 512 + lane * 8));
#pragma unroll
        for (int r = 0; r < WR1; ++r)
#pragma unroll
            for (int c = 0; c < WC2; ++c)
                acc2[r][c] = __builtin_amdgcn_mfma_f32_16x16x32_bf16(a[r], bw[c], acc2[r][c], 0, 0, 0);
    }

    if constexpr (C3 == 0) {
        // ---- final epilogue from acc2 ----
#pragma unroll
        for (int c = 0; c < WC2; ++c) {
            int col = c * 16 + m16;
            float sc = sc2[col], sh = sh2[col];
#pragma unroll
            for (int r = 0; r < WR1; ++r) {
                int row0 = base + r * 16 + quad * 4;
#pragma unroll
                for (int i = 0; i < 4; ++i) {
                    float v = acc2[r][c][i] * sc + sh;
                    v = v > 0.f ? v : 0.f;
                    size_t off = (size_t)(row0 + i) * ystride + yoff + col;
                    if (Yf) Yf[off] = v;
                    else    Y[off] = (bf16)v;
                }
            }
        }
    } else {
        // ---- stage-2 epilogue -> Lt (reuse; compiler orders ds ops) ----
#pragma unroll
        for (int c = 0; c < WC2; ++c) {
            int col = c * 16 + m16;
            float sc = sc2[col], sh = sh2[col];
#pragma unroll
            for (int r = 0; r < WR1; ++r) {
                int row0 = r * 16 + quad * 4;
#pragma unroll
                for (int i = 0; i < 4; ++i) {
                    float v = acc2[r][c][i] * sc + sh;
                    v = v > 0.f ? v : 0.f;
                    Lt[(row0 + i) * LS2 + col] = (bf16)v;
                }
            }
        }

        constexpr int C3v = (C3 > 0) ? C3 : 16;
        constexpr int NT3 = C3v / 16;
        constexpr int WC3 = NT3;
        constexpr int KS3 = C2 / 32;

        f32x4 acc3[WR1][WC3];
#pragma unroll
        for (int r = 0; r < WR1; ++r)
#pragma unroll
            for (int c = 0; c < WC3; ++c) acc3[r][c] = (f32x4){0.f, 0.f, 0.f, 0.f};

#pragma unroll
        for (int s3 = 0; s3 < KS3; ++s3) {
            bf16x8 a[WR1], bw[WC3];
#pragma unroll
            for (int r = 0; r < WR1; ++r)
                a[r] = *(const bf16x8*)(&Lt[(r * 16 + m16) * LS2 + s3 * 32 + quad * 8]);
#pragma unroll
            for (int c = 0; c < WC3; ++c)
                bw[c] = *(const bf16x8*)(W3 + ((s3 * NT3 + c) * 512 + lane * 8));
#pragma unroll
            for (int r = 0; r < WR1; ++r)
#pragma unroll
                for (int c = 0; c < WC3; ++c)
                    acc3[r][c] = __builtin_amdgcn_mfma_f32_16x16x32_bf16(a[r], bw[c], acc3[r][c], 0, 0, 0);
        }

#pragma unroll
        for (int c = 0; c < WC3; ++c) {
            int col = c * 16 + m16;
            float sc = sc3[col], sh = sh3[col];
#pragma unroll
            for (int r = 0; r < WR1; ++r) {
                int row0 = base + r * 16 + quad * 4;
#pragma unroll
                for (int i = 0; i < 4; ++i) {
                    float v = acc3[r][c][i] * sc + sh;
                    v = v > 0.f ? v : 0.f;
                    size_t off = (size_t)(row0 + i) * ystride + yoff + col;
                    if (Yf) Yf[off] = v;
                    else    Y[off] = (bf16)v;
                }
            }
        }
    }
}

// ---------------------------------------------------------------------------
// z[:, 64:96] = sanitize(y2[align_idx])  (features_at_coordinates + concat)
// ---------------------------------------------------------------------------
__global__ void concat_kernel(const bf16* __restrict__ y2, const int* __restrict__ align,
                              bf16* __restrict__ z, int n) {
    int e = blockIdx.x * 256 + threadIdx.x;   // over n*32
    if (e >= n * 32) return;
    int i = e >> 5, c = e & 31;
    int a = align[i];
    float v = (float)y2[(size_t)a * 32 + c];
    unsigned u = __builtin_bit_cast(unsigned, v);
    if ((u & 0x7f800000u) == 0x7f800000u) v = 0.f;   // NaN/Inf -> 0
    z[(size_t)i * 96 + 64 + c] = (bf16)v;
}

// ---------------------------------------------------------------------------
extern "C" void kernel_launch(void* const* d_in, const int* in_sizes, int n_in,
                              void* d_out, int out_size, void* d_ws, size_t ws_size,
                              hipStream_t stream) {
    const float* feat3d = (const float*)d_in[0];
    const float* feat2d = (const float*)d_in[1];
    const float* Wsrc[11];
    for (int i = 0; i < 11; ++i) Wsrc[i] = (const float*)d_in[2 + i];
    const float* bn[22];
    for (int i = 0; i < 22; ++i) bn[i] = (const float*)d_in[13 + i];
    const int* nbr   = (const int*)d_in[35];
    const int* align = (const int*)d_in[36];
    float* out = (float*)d_out;

    const int n = in_sizes[0] / 96;   // 80000, divisible by 64 and 32

    // workspace layout
    char* ws = (char*)d_ws;
    size_t off = 0;
    auto alloc = [&](size_t bytes) -> void* {
        void* p = ws + off;
        off = (off + bytes + 255) & ~(size_t)255;
        return p;
    };
    bf16* F3 = (bf16*)alloc((size_t)n * 96 * 2);
    bf16* F2 = (bf16*)alloc((size_t)n * 256 * 2);
    static const int wt_taps[11] = {27, 1, 27, 1, 27, 1, 27, 1, 27, 1, 1};
    static const int wt_cin[11]  = {96, 64, 64, 64, 256, 64, 64, 32, 96, 128, 128};
    static const int wt_cout[11] = {64, 64, 64, 64, 64, 64, 32, 32, 128, 128, 128};
    bf16* Wf[11];
    for (int i = 0; i < 11; ++i)
        Wf[i] = (bf16*)alloc((size_t)wt_taps[i] * wt_cin[i] * wt_cout[i] * 2);
    bf16* tA = (bf16*)alloc((size_t)n * 64 * 2);
    bf16* tB = (bf16*)alloc((size_t)n * 64 * 2);
    bf16* y2 = (bf16*)alloc((size_t)n * 32 * 2);
    bf16* z  = (bf16*)alloc((size_t)n * 96 * 2);

    // ---- prep: converts + weight swizzles ----
    f2b_kernel<<<(n * 96 / 4 + 255) / 256, 256, 0, stream>>>(feat3d, F3, n * 96 / 4);
    f2b_kernel<<<(n * 256 / 4 + 255) / 256, 256, 0, stream>>>(feat2d, F2, n * 256 / 4);
    for (int i = 0; i < 11; ++i) {
        int total = wt_taps[i] * wt_cin[i] * wt_cout[i];
        swz_kernel<<<(total + 255) / 256, 256, 0, stream>>>(Wsrc[i], Wf[i], wt_cin[i], wt_cout[i], total);
    }

    const int GB64 = n / 64;   // 1250 one-wave blocks (WR=4)
    const int GB32 = n / 32;   // 2500 one-wave blocks (WR=2, c-layer)

    // ---- 3D branch: (a1+a2), (a3+a4) ----
    layer_kernel<96, 64, 27, 64, 0><<<GB64, 64, 0, stream>>>(
        F3, Wf[0], Wf[1], nullptr, nbr,
        bn[0], bn[1], bn[2], bn[3], nullptr, nullptr,
        tB, nullptr, 64, 0, n, GB64);
    layer_kernel<64, 64, 27, 64, 0><<<GB64, 64, 0, stream>>>(
        tB, Wf[2], Wf[3], nullptr, nbr,
        bn[4], bn[5], bn[6], bn[7], nullptr, nullptr,
        z, nullptr, 96, 0, n, GB64);               // x3 -> z[:,0:64]

    // ---- 2D branch: (b1+b2), (b3+b4) ----
    layer_kernel<256, 64, 27, 64, 0><<<GB64, 64, 0, stream>>>(
        F2, Wf[4], Wf[5], nullptr, nbr,
        bn[8], bn[9], bn[10], bn[11], nullptr, nullptr,
        tA, nullptr, 64, 0, n, GB64);
    layer_kernel<64, 32, 27, 32, 0><<<GB64, 64, 0, stream>>>(
        tA, Wf[6], Wf[7], nullptr, nbr,
        bn[12], bn[13], bn[14], bn[15], nullptr, nullptr,
        y2, nullptr, 32, 0, n, GB64);

    // ---- align gather + concat into z[:,64:96] ----
    concat_kernel<<<(n * 32 + 255) / 256, 256, 0, stream>>>(y2, align, z, n);

    // ---- fusion: (c1+c2+c3) ----
    layer_kernel<96, 128, 27, 128, 128><<<GB32, 64, 0, stream>>>(
        z, Wf[8], Wf[9], Wf[10], nbr,
        bn[16], bn[17], bn[18], bn[19], bn[20], bn[21],
        nullptr, out, 128, 0, n, GB32);
}

// Round 5
// 589.864 us; speedup vs baseline: 1.0699x; 1.0699x over previous
//
#include <hip/hip_runtime.h>

typedef __bf16 bf16;
typedef __bf16 bf16x8 __attribute__((ext_vector_type(8)));
typedef __bf16 bf16x4 __attribute__((ext_vector_type(4)));
typedef float  f32x4  __attribute__((ext_vector_type(4)));

// ---------------------------------------------------------------------------
// f32 -> bf16 convert, 4-wide
// ---------------------------------------------------------------------------
__global__ void f2b_kernel(const float* __restrict__ src, bf16* __restrict__ dst, int n4) {
    int i = blockIdx.x * 256 + threadIdx.x;
    if (i >= n4) return;
    float4 v = ((const float4*)src)[i];
    bf16x4 o = { (bf16)v.x, (bf16)v.y, (bf16)v.z, (bf16)v.w };
    ((bf16x4*)dst)[i] = o;
}

// ---------------------------------------------------------------------------
// Swizzle fp32 W (taps, cin, cout) into bf16 MFMA-B-fragment order:
//   Wf[tap][s][nt][lane][j] = W[tap][s*32 + (lane>>4)*8 + j][nt*16 + (lane&15)]
// ---------------------------------------------------------------------------
__global__ void swz_kernel(const float* __restrict__ W, bf16* __restrict__ Wf,
                           int cin, int cout, int total) {
    int e = blockIdx.x * 256 + threadIdx.x;
    if (e >= total) return;
    int per_tap = cin * cout;
    int tap = e / per_tap;
    int t2  = e - tap * per_tap;
    int ntc = cout >> 4;               // number of 16-col tiles
    int s   = t2 / (ntc * 512);        // K-step of 32
    int r3  = t2 - s * (ntc * 512);
    int nt  = r3 >> 9;
    int L   = (r3 & 511) >> 3;
    int j   = r3 & 7;
    int k   = s * 32 + (L >> 4) * 8 + j;
    int col = nt * 16 + (L & 15);
    Wf[e] = (bf16)W[((size_t)tap * cin + k) * cout + col];
}

// ---------------------------------------------------------------------------
// ROUND-5 STRUCTURE: tap-split wave parallelism.
// R4 post-mortem: zero-barrier single-wave design removed gang-stalls and
// bank conflicts but Occupancy=12.6% (1.2 waves/SIMD) left gather latency
// (~600-900cy) fully exposed (per-step prefetch slack is only ~80cy of
// MFMA). Fix: 4 waves per block SPLIT THE 27 TAPS (7/7/7/6) over the SAME
// row-tile -- gather+weight traffic unchanged, wave count x4 (5000 waves,
// ~12 waves/CU at 3 blocks/CU) so TLP hides the latency. Main loop is
// unchanged from R4 (independent per-wave, gather straight to VGPR, zero
// barriers). Partial accumulators combine once per layer via a 2-pass f32
// LDS reduction that directly emits the bn-relu'd h1 tile; dense stages
// split rows (RW=64: 16 rows/wave) or rows x col-groups (RW=32, C>=128).
// ---------------------------------------------------------------------------
template<int CIN, int C1, int TAPS, int C2, int C3>
__global__ __launch_bounds__(256, 3) void layer_kernel(
    const bf16* __restrict__ X,
    const bf16* __restrict__ W1,     // swizzled (TAPS*CIN/32, C1/16, 512)
    const bf16* __restrict__ W2,     // swizzled (C1/32, C2/16, 512)
    const bf16* __restrict__ W3,     // swizzled (C2/32, C3/16, 512) or null
    const int*  __restrict__ nbr,    // (TAPS, n)
    const float* __restrict__ sc1, const float* __restrict__ sh1,
    const float* __restrict__ sc2, const float* __restrict__ sh2,
    const float* __restrict__ sc3, const float* __restrict__ sh3,
    bf16* __restrict__ Y, float* __restrict__ Yf,
    int ystride, int yoff, int n, int nblocks)
{
    constexpr int NT1 = C1 / 16;
    constexpr int WC1 = NT1;                 // wave covers full output width
    constexpr int RW  = (C1 >= 128) ? 32 : 64;   // rows per block tile
    constexpr int WR1 = RW / 16;             // row fragments per wave
    constexpr int KS  = CIN / 32;            // K-slices per tap
    constexpr int LS1 = C1 + 8;
    constexpr int LS2 = C2 + 8;
    constexpr int HC  = C1 / 2;              // half-columns per reduce pass
    constexpr int HCP = HC + 1;              // padded stride (bank spread)
    constexpr int PRB = 4 * RW * HCP * 4;    // partial-reduce buffer bytes
    constexpr int LTB = RW * LS1 * 2;
    constexpr bool BPRE = (WC1 <= 4);        // double-buffer B-frags? (VGPR)

    __shared__ __align__(16) char smem[PRB + LTB];
    float* PR  = (float*)smem;               // 4 x RW x HCP f32 partials
    bf16*  Lt  = (bf16*)(smem + PRB);        // h1 tile (RW x LS1)
    bf16*  Lt2 = (bf16*)smem;                // h2 tile, aliases PR (safe: PR dead)

    const int tid  = threadIdx.x;
    const int lane = tid & 63;
    const int wv   = tid >> 6;
    const int m16  = lane & 15;
    const int quad = lane >> 4;

    // XCD-contiguous block swizzle (bijection, m204 form)
    const int bq = nblocks >> 3, br = nblocks & 7;
    const int bx = blockIdx.x & 7, bs = blockIdx.x >> 3;
    const int sb = bx * bq + (bx < br ? bx : br) + bs;
    const int base = sb * RW;

    // this wave's tap range (7/7/7/6 for TAPS=27)
    constexpr int TB = TAPS / 4, TR = TAPS % 4;
    const int tstart = wv * TB + (wv < TR ? wv : TR);
    const int tcnt   = TB + (wv < TR ? 1 : 0);
    const int TOTW   = tcnt * KS;

    const bf16x8 ZB = __builtin_bit_cast(bf16x8, (float4){0.f, 0.f, 0.f, 0.f});

    int idxc[WR1], idxn[WR1];
    auto load_idx = [&](int t, int (&id)[WR1]) {
#pragma unroll
        for (int r = 0; r < WR1; ++r)
            id[r] = nbr[(size_t)t * n + base + r * 16 + m16];
    };
    auto load_b = [&](int gstep, bf16x8 (&b)[WC1]) {
        const bf16* wt = W1 + (size_t)gstep * (NT1 * 512) + lane * 8;
#pragma unroll
        for (int c = 0; c < WC1; ++c)
            b[c] = *(const bf16x8*)(wt + c * 512);
    };

    f32x4 acc1[WR1][WC1];
#pragma unroll
    for (int r = 0; r < WR1; ++r)
#pragma unroll
        for (int c = 0; c < WC1; ++c) acc1[r][c] = (f32x4){0.f, 0.f, 0.f, 0.f};

    bf16x8 aA[WR1], aB[WR1], bA[WC1], bB[WC1];

    // prologue: gathers+weights for local step 0; indices for first two taps
    load_idx(tstart, idxc);
    if (tcnt > 1) load_idx(tstart + 1, idxn);
    if constexpr (BPRE) load_b(tstart * KS, bA);
#pragma unroll
    for (int r = 0; r < WR1; ++r) {
        bf16x8 v = ZB;
        if (idxc[r] >= 0) v = *(const bf16x8*)(X + (size_t)(unsigned)idxc[r] * CIN + quad * 8);
        aA[r] = v;
    }

    int tloc = 0, s = 0;
    auto dostep = [&](int it, bf16x8 (&aC)[WR1], bf16x8 (&bC)[WC1],
                      bf16x8 (&aN)[WR1], bf16x8 (&bN)[WC1]) {
        int s1 = s + 1, tl1 = tloc;
        bool wrap = (s1 == KS);
        if (wrap) { s1 = 0; ++tl1; }
        if (it + 1 < TOTW) {
            if constexpr (BPRE) load_b((tstart + tl1) * KS + s1, bN);
#pragma unroll
            for (int r = 0; r < WR1; ++r) {          // next-step gather
                int id_ = wrap ? idxn[r] : idxc[r];
                bf16x8 v = ZB;
                if (id_ >= 0) v = *(const bf16x8*)(X + (size_t)(unsigned)id_ * CIN + s1 * 32 + quad * 8);
                aN[r] = v;
            }
        }
        if constexpr (!BPRE) load_b((tstart + tloc) * KS + s, bC);
#pragma unroll
        for (int r = 0; r < WR1; ++r)
#pragma unroll
            for (int c = 0; c < WC1; ++c)
                acc1[r][c] = __builtin_amdgcn_mfma_f32_16x16x32_bf16(aC[r], bC[c], acc1[r][c], 0, 0, 0);
        if (wrap) {
#pragma unroll
            for (int r = 0; r < WR1; ++r) idxc[r] = idxn[r];
            if (tloc + 2 < tcnt) load_idx(tstart + tloc + 2, idxn);
        }
        tloc = tl1; s = s1;
    };

    for (int it = 0; it < TOTW; it += 2) {
        dostep(it, aA, bA, aB, bB);
        if (it + 1 < TOTW) dostep(it + 1, aB, bB, aA, bA);
    }

    // ---- cross-wave tap reduction (2 half-column passes) -> bnrelu -> Lt ----
    constexpr int SLICE = RW / 4;            // rows summed per wave
#pragma unroll
    for (int p = 0; p < 2; ++p) {
        __syncthreads();                     // converge / WAR on PR
        float* Pw = PR + wv * (RW * HCP);
#pragma unroll
        for (int c = 0; c < WC1 / 2; ++c)
#pragma unroll
            for (int r = 0; r < WR1; ++r)
#pragma unroll
                for (int i = 0; i < 4; ++i)
                    Pw[(r * 16 + quad * 4 + i) * HCP + c * 16 + m16] = acc1[r][p * (WC1 / 2) + c][i];
        __syncthreads();
#pragma unroll
        for (int e = lane; e < SLICE * HC; e += 64) {
            int row  = wv * SLICE + e / HC;
            int colh = e & (HC - 1);
            float v = PR[(0 * RW + row) * HCP + colh] + PR[(1 * RW + row) * HCP + colh]
                    + PR[(2 * RW + row) * HCP + colh] + PR[(3 * RW + row) * HCP + colh];
            int col = p * HC + colh;
            v = v * sc1[col] + sh1[col];
            v = v > 0.f ? v : 0.f;
            Lt[row * LS1 + col] = (bf16)v;
        }
    }
    __syncthreads();                         // Lt complete

    // ---- dense stage 2: wave -> (row group, col group) ----
    constexpr int NT2  = C2 / 16;
    constexpr int DRW  = RW / 16 >= 4 ? 4 : RW / 16;  // 4 (RW=64) or 2 (RW=32)
    constexpr int NCG  = 4 / DRW;                     // col groups: 1 or 2
    constexpr int WC2g = NT2 / NCG;
    constexpr int KS2  = C1 / 32;
    const int wr  = wv % DRW;
    const int wcg = wv / DRW;

    f32x4 acc2[WC2g];
#pragma unroll
    for (int c = 0; c < WC2g; ++c) acc2[c] = (f32x4){0.f, 0.f, 0.f, 0.f};

#pragma unroll
    for (int s2 = 0; s2 < KS2; ++s2) {
        bf16x8 a = *(const bf16x8*)(&Lt[(wr * 16 + m16) * LS1 + s2 * 32 + quad * 8]);
        bf16x8 bw[WC2g];
#pragma unroll
        for (int c = 0; c < WC2g; ++c)
            bw[c] = *(const bf16x8*)(W2 + ((s2 * NT2 + wcg * WC2g + c) * 512 + lane * 8));
#pragma unroll
        for (int c = 0; c < WC2g; ++c)
            acc2[c] = __builtin_amdgcn_mfma_f32_16x16x32_bf16(a, bw[c], acc2[c], 0, 0, 0);
    }

    if constexpr (C3 == 0) {
#pragma unroll
        for (int c = 0; c < WC2g; ++c) {
            int col = (wcg * WC2g + c) * 16 + m16;
            float sc = sc2[col], sh = sh2[col];
            int row0 = base + wr * 16 + quad * 4;
#pragma unroll
            for (int i = 0; i < 4; ++i) {
                float v = acc2[c][i] * sc + sh;
                v = v > 0.f ? v : 0.f;
                size_t off = (size_t)(row0 + i) * ystride + yoff + col;
                if (Yf) Yf[off] = v;
                else    Y[off] = (bf16)v;
            }
        }
    } else {
        // ---- stage-2 epilogue -> Lt2 (aliases dead PR region) ----
#pragma unroll
        for (int c = 0; c < WC2g; ++c) {
            int col = (wcg * WC2g + c) * 16 + m16;
            float sc = sc2[col], sh = sh2[col];
            int row0 = wr * 16 + quad * 4;
#pragma unroll
            for (int i = 0; i < 4; ++i) {
                float v = acc2[c][i] * sc + sh;
                v = v > 0.f ? v : 0.f;
                Lt2[(row0 + i) * LS2 + col] = (bf16)v;
            }
        }
        __syncthreads();                     // Lt2 complete

        constexpr int C3v  = (C3 > 0) ? C3 : 16;
        constexpr int NT3  = C3v / 16;
        constexpr int WC3g = NT3 / NCG;
        constexpr int KS3  = C2 / 32;

        f32x4 acc3[WC3g];
#pragma unroll
        for (int c = 0; c < WC3g; ++c) acc3[c] = (f32x4){0.f, 0.f, 0.f, 0.f};

#pragma unroll
        for (int s3 = 0; s3 < KS3; ++s3) {
            bf16x8 a = *(const bf16x8*)(&Lt2[(wr * 16 + m16) * LS2 + s3 * 32 + quad * 8]);
            bf16x8 bw[WC3g];
#pragma unroll
            for (int c = 0; c < WC3g; ++c)
                bw[c] = *(const bf16x8*)(W3 + ((s3 * NT3 + wcg * WC3g + c) * 512 + lane * 8));
#pragma unroll
            for (int c = 0; c < WC3g; ++c)
                acc3[c] = __builtin_amdgcn_mfma_f32_16x16x32_bf16(a, bw[c], acc3[c], 0, 0, 0);
        }

#pragma unroll
        for (int c = 0; c < WC3g; ++c) {
            int col = (wcg * WC3g + c) * 16 + m16;
            float sc = sc3[col], sh = sh3[col];
            int row0 = base + wr * 16 + quad * 4;
#pragma unroll
            for (int i = 0; i < 4; ++i) {
                float v = acc3[c][i] * sc + sh;
                v = v > 0.f ? v : 0.f;
                size_t off = (size_t)(row0 + i) * ystride + yoff + col;
                if (Yf) Yf[off] = v;
                else    Y[off] = (bf16)v;
            }
        }
    }
}

// ---------------------------------------------------------------------------
// z[:, 64:96] = sanitize(y2[align_idx])  (features_at_coordinates + concat)
// ---------------------------------------------------------------------------
__global__ void concat_kernel(const bf16* __restrict__ y2, const int* __restrict__ align,
                              bf16* __restrict__ z, int n) {
    int e = blockIdx.x * 256 + threadIdx.x;   // over n*32
    if (e >= n * 32) return;
    int i = e >> 5, c = e & 31;
    int a = align[i];
    float v = (float)y2[(size_t)a * 32 + c];
    unsigned u = __builtin_bit_cast(unsigned, v);
    if ((u & 0x7f800000u) == 0x7f800000u) v = 0.f;   // NaN/Inf -> 0
    z[(size_t)i * 96 + 64 + c] = (bf16)v;
}

// ---------------------------------------------------------------------------
extern "C" void kernel_launch(void* const* d_in, const int* in_sizes, int n_in,
                              void* d_out, int out_size, void* d_ws, size_t ws_size,
                              hipStream_t stream) {
    const float* feat3d = (const float*)d_in[0];
    const float* feat2d = (const float*)d_in[1];
    const float* Wsrc[11];
    for (int i = 0; i < 11; ++i) Wsrc[i] = (const float*)d_in[2 + i];
    const float* bn[22];
    for (int i = 0; i < 22; ++i) bn[i] = (const float*)d_in[13 + i];
    const int* nbr   = (const int*)d_in[35];
    const int* align = (const int*)d_in[36];
    float* out = (float*)d_out;

    const int n = in_sizes[0] / 96;   // 80000, divisible by 64 and 32

    // workspace layout
    char* ws = (char*)d_ws;
    size_t off = 0;
    auto alloc = [&](size_t bytes) -> void* {
        void* p = ws + off;
        off = (off + bytes + 255) & ~(size_t)255;
        return p;
    };
    bf16* F3 = (bf16*)alloc((size_t)n * 96 * 2);
    bf16* F2 = (bf16*)alloc((size_t)n * 256 * 2);
    static const int wt_taps[11] = {27, 1, 27, 1, 27, 1, 27, 1, 27, 1, 1};
    static const int wt_cin[11]  = {96, 64, 64, 64, 256, 64, 64, 32, 96, 128, 128};
    static const int wt_cout[11] = {64, 64, 64, 64, 64, 64, 32, 32, 128, 128, 128};
    bf16* Wf[11];
    for (int i = 0; i < 11; ++i)
        Wf[i] = (bf16*)alloc((size_t)wt_taps[i] * wt_cin[i] * wt_cout[i] * 2);
    bf16* tA = (bf16*)alloc((size_t)n * 64 * 2);
    bf16* tB = (bf16*)alloc((size_t)n * 64 * 2);
    bf16* y2 = (bf16*)alloc((size_t)n * 32 * 2);
    bf16* z  = (bf16*)alloc((size_t)n * 96 * 2);

    // ---- prep: converts + weight swizzles ----
    f2b_kernel<<<(n * 96 / 4 + 255) / 256, 256, 0, stream>>>(feat3d, F3, n * 96 / 4);
    f2b_kernel<<<(n * 256 / 4 + 255) / 256, 256, 0, stream>>>(feat2d, F2, n * 256 / 4);
    for (int i = 0; i < 11; ++i) {
        int total = wt_taps[i] * wt_cin[i] * wt_cout[i];
        swz_kernel<<<(total + 255) / 256, 256, 0, stream>>>(Wsrc[i], Wf[i], wt_cin[i], wt_cout[i], total);
    }

    const int GB64 = n / 64;   // 1250 blocks x 4 tap-split waves
    const int GB32 = n / 32;   // 2500 blocks (c-layer, RW=32)

    // ---- 3D branch: (a1+a2), (a3+a4) ----
    layer_kernel<96, 64, 27, 64, 0><<<GB64, 256, 0, stream>>>(
        F3, Wf[0], Wf[1], nullptr, nbr,
        bn[0], bn[1], bn[2], bn[3], nullptr, nullptr,
        tB, nullptr, 64, 0, n, GB64);
    layer_kernel<64, 64, 27, 64, 0><<<GB64, 256, 0, stream>>>(
        tB, Wf[2], Wf[3], nullptr, nbr,
        bn[4], bn[5], bn[6], bn[7], nullptr, nullptr,
        z, nullptr, 96, 0, n, GB64);               // x3 -> z[:,0:64]

    // ---- 2D branch: (b1+b2), (b3+b4) ----
    layer_kernel<256, 64, 27, 64, 0><<<GB64, 256, 0, stream>>>(
        F2, Wf[4], Wf[5], nullptr, nbr,
        bn[8], bn[9], bn[10], bn[11], nullptr, nullptr,
        tA, nullptr, 64, 0, n, GB64);
    layer_kernel<64, 32, 27, 32, 0><<<GB64, 256, 0, stream>>>(
        tA, Wf[6], Wf[7], nullptr, nbr,
        bn[12], bn[13], bn[14], bn[15], nullptr, nullptr,
        y2, nullptr, 32, 0, n, GB64);

    // ---- align gather + concat into z[:,64:96] ----
    concat_kernel<<<(n * 32 + 255) / 256, 256, 0, stream>>>(y2, align, z, n);

    // ---- fusion: (c1+c2+c3) ----
    layer_kernel<96, 128, 27, 128, 128><<<GB32, 256, 0, stream>>>(
        z, Wf[8], Wf[9], Wf[10], nbr,
        bn[16], bn[17], bn[18], bn[19], bn[20], bn[21],
        nullptr, out, 128, 0, n, GB32);
}